// Round 9
// baseline (283.488 us; speedup 1.0000x reference)
//
#include <hip/hip_runtime.h>
#include <math.h>

// ---------------------------------------------------------------------------
// Model: conv1(5x5,20)+pool2 -> conv2(5x5,50)+pool2 -> pcaps(5x5 pad2,16)
//        -> squash -> priors -> dynamic routing(3) -> fc1(relu) -> fc2
// B=2048. conv1/conv2/pcaps/fc1 via bf16 MFMA (16x16x32).
// k_convs: conv1 A-frags built register-direct from xbf (no im2col LDS, no
// barriers); conv2 in 2 m-passes (lower VGPR) -> 4 blocks/CU @ 40448 B LDS.
// k_fc1: 32x64 tile, grid 512 (2 blocks/CU), LDS double-buffer, 1 barrier/iter,
// fused fc2 epilogue via atomics into pre-initialized out.
// h_bf global layout POSITION-MAJOR: k' = pos*50 + oc, padded to 3616.
// ---------------------------------------------------------------------------

#define BATCH 2048

typedef __attribute__((ext_vector_type(8))) short short8;
typedef __attribute__((ext_vector_type(4))) float floatx4;
typedef unsigned short u16;
typedef unsigned int   u32;

__device__ inline float wave_sum(float v) {
#pragma unroll
    for (int off = 32; off >= 1; off >>= 1) v += __shfl_xor(v, off);
    return v;
}
__device__ inline float wave_max(float v) {
#pragma unroll
    for (int off = 32; off >= 1; off >>= 1) v = fmaxf(v, __shfl_xor(v, off));
    return v;
}
__device__ inline u16 f2bf(float f) {  // RNE fp32->bf16 (finite)
    u32 u = __float_as_uint(f);
    u32 r = (u + 0x7FFFu + ((u >> 16) & 1u)) >> 16;
    return (u16)r;
}
// extract 5 consecutive u16 starting at index par (0/1) from a short8
__device__ inline void ext5(short8 v, int par, u16 e[5]) {
    union { short8 s; u16 a[8]; } u; u.s = v;
#pragma unroll
    for (int s5 = 0; s5 < 5; ++s5)
        e[s5] = par ? u.a[s5 + 1] : u.a[s5];
}

// ---------- Kernel 0: weight conversions + out init ------------------------
__global__ __launch_bounds__(256) void k_prep(
    const float* __restrict__ fw,  u16* __restrict__ w_bf,
    const float* __restrict__ w2,  u16* __restrict__ w2t,
    const float* __restrict__ pcw, u16* __restrict__ w_pc,
    const float* __restrict__ w1,  u16* __restrict__ w1t,
    const float* __restrict__ y,   const float* __restrict__ f2w,
    const float* __restrict__ f2b, float* __restrict__ out)
{
    __shared__ __align__(16) float srow[3600];
    const int blk = blockIdx.x, t = threadIdx.x;
    if (blk < 500) {
        const int n = blk;
        const float* src = fw + (size_t)n * 3602;
        for (int i = t; i < 1800; i += 256)
            *(float2*)&srow[2 * i] = *(const float2*)&src[2 * i];
        __syncthreads();
        u32* dst = (u32*)(w_bf + (size_t)n * 3616);
        for (int i = t; i < 1808; i += 256) {
            int k2 = 2 * i;
            u32 pk = 0u;
            if (k2 < 3600) {
                int pos = k2 / 50, oc = k2 - 50 * pos;
                pk = (u32)f2bf(srow[oc * 72 + pos])
                   | ((u32)f2bf(srow[(oc + 1) * 72 + pos]) << 16);
            }
            dst[i] = pk;
        }
    } else if (blk == 500) {
        u32* z = (u32*)(w_bf + (size_t)500 * 3616);
        for (int i = t; i < 21696; i += 256) z[i] = 0u;
    } else if (blk < 526) {
        int g   = (blk - 501) * 256 + t;
        int idx = g * 8;
        int tap = idx >> 11;
        int oc  = (idx >> 5) & 63;
        int ic0 = idx & 31;
        u16 v[8];
#pragma unroll
        for (int j = 0; j < 8; ++j) {
            int ic = ic0 + j;
            float f = (ic < 20 && oc < 50) ? w2[oc * 500 + ic * 25 + tap] : 0.f;
            v[j] = f2bf(f);
        }
        *(short8*)&w2t[idx] = *(short8*)v;
    } else if (blk < 539) {
        int g = (blk - 526) * 256 + t;
        if (g >= 3200) return;
        int idx = g * 8;
        int tap = idx >> 10;
        int rem = idx & 1023;
        int oc  = rem >> 6;
        int ic0 = rem & 63;
        u16 v[8];
#pragma unroll
        for (int j = 0; j < 8; ++j) {
            int ic = ic0 + j;
            float f = (ic < 50) ? pcw[(oc * 50 + ic) * 25 + tap] : 0.f;
            v[j] = f2bf(f);
        }
        *(short8*)&w_pc[idx] = *(short8*)v;
    } else if (blk == 539) {
        if (t < 128) {
            int n  = t >> 2;
            int k0 = (t & 3) * 8;
            u16 v[8];
#pragma unroll
            for (int j = 0; j < 8; ++j) {
                int k = k0 + j;
                float f = (n < 20 && k < 25) ? w1[n * 25 + k] : 0.f;
                v[j] = f2bf(f);
            }
            *(short8*)&w1t[t * 8] = *(short8*)v;
        }
    } else {
        int b = (blk - 540) * 256 + t;   // 0..2047
        float y0 = y[b * 2], y1 = y[b * 2 + 1];
        float2 o;
        o.x = f2b[0] + y0 * f2w[500] + y1 * f2w[501];
        o.y = f2b[1] + y0 * f2w[502 + 500] + y1 * f2w[502 + 501];
        *(float2*)&out[b * 2] = o;
    }
}

// ---------- Kernel 1: conv1+conv2 (MFMA) + pcaps (MFMA) + routing ----------
// LDS (40448 B union):
//   conv phase : h1t[448][40] u16 @0 (35840 B) | xbf[36][64] u16 @35840
//   pcaps phase: hs2 f32[3600] @0 | hsbuf u16[176][72] @14400 B
//                psum f32[5120] overlays hsbuf | pri f32[576] @34880 B
__global__ __launch_bounds__(256, 4) void k_convs(
    const float* __restrict__ x, const u16* __restrict__ w1t,
    const float* __restrict__ b1, const u16* __restrict__ w2t,
    const float* __restrict__ b2, const u16* __restrict__ w_pc,
    const float* __restrict__ pcb, const float* __restrict__ rw,
    u32* __restrict__ h_bf, float* __restrict__ cbuf)
{
    __shared__ __align__(16) u16 smem[20224];   // 40448 B
    u16* h1t = smem;            // 17920 shorts
    u16* xbf = smem + 17920;    // 2304 shorts ([36][64])

    const int t = threadIdx.x;
    const int b = blockIdx.x;

    // zero the ic pad [20,32) of h1t rows; stage x as bf16
    for (int i = t; i < 2688; i += 256) {
        int pos = i / 6, c = i - 6 * pos;
        ((u32*)h1t)[pos * 20 + 10 + c] = 0u;
    }
    const float* xb = x + b * 2160;
    for (int i = t; i < 2160; i += 256) {
        int r = i / 60, c = i - 60 * r;
        xbf[r * 64 + c] = f2bf(xb[i]);
    }
    __syncthreads();

    const int lane = t & 63, w = t >> 6;
    const int r16  = lane & 15;
    const int q    = lane >> 4;

    // ---- conv1 via MFMA: 112 jobs (16 chunks x 7 m-tiles), barrier-free ----
    // A-frag built in registers straight from xbf. Lane (r16,q) supplies
    // A row m = mt*16+r16 (position p), taps q*8..q*8+7.
    short8 w1f[2];
#pragma unroll
    for (int nt = 0; nt < 2; ++nt)
        w1f[nt] = *(const short8*)&w1t[(nt * 16 + r16) * 32 + q * 8];

#pragma unroll 1
    for (int jj = 0; jj < 28; ++jj) {
        int jb = w + 4 * jj;          // 0..111
        int mt = jb % 7;
        int c  = jb / 7;
        int p  = mt * 16 + r16;
        int px = p >> 2;
        int dy = (p >> 1) & 1, dx = p & 1;
        int xc = 2 * px + dx;         // 0..55
        int par = xc & 1;
        int rowbase = (2 * c + dy) * 64 + (xc & ~1);
        union { short8 s; u16 a[8]; } af;
        if (q == 0) {                 // taps: r0 s0-4, r1 s0-2
            short8 vA = *(const short8*)&xbf[rowbase];
            short8 vB = *(const short8*)&xbf[rowbase + 64];
            u16 eA[5], eB[5];
            ext5(vA, par, eA); ext5(vB, par, eB);
            af.a[0]=eA[0]; af.a[1]=eA[1]; af.a[2]=eA[2]; af.a[3]=eA[3];
            af.a[4]=eA[4]; af.a[5]=eB[0]; af.a[6]=eB[1]; af.a[7]=eB[2];
        } else if (q == 1) {          // taps: r1 s3-4, r2 s0-4, r3 s0
            short8 vB = *(const short8*)&xbf[rowbase + 64];
            short8 vC = *(const short8*)&xbf[rowbase + 128];
            short8 vD = *(const short8*)&xbf[rowbase + 192];
            u16 eB[5], eC[5], eD[5];
            ext5(vB, par, eB); ext5(vC, par, eC); ext5(vD, par, eD);
            af.a[0]=eB[3]; af.a[1]=eB[4]; af.a[2]=eC[0]; af.a[3]=eC[1];
            af.a[4]=eC[2]; af.a[5]=eC[3]; af.a[6]=eC[4]; af.a[7]=eD[0];
        } else if (q == 2) {          // taps: r3 s1-4, r4 s0-3
            short8 vD = *(const short8*)&xbf[rowbase + 192];
            short8 vE = *(const short8*)&xbf[rowbase + 256];
            u16 eD[5], eE[5];
            ext5(vD, par, eD); ext5(vE, par, eE);
            af.a[0]=eD[1]; af.a[1]=eD[2]; af.a[2]=eD[3]; af.a[3]=eD[4];
            af.a[4]=eE[0]; af.a[5]=eE[1]; af.a[6]=eE[2]; af.a[7]=eE[3];
        } else {                      // tap 24 = r4 s4; 25..31 hit zero B rows
            short8 vE = *(const short8*)&xbf[rowbase + 256];
            u16 eE[5];
            ext5(vE, par, eE);
            af.a[0]=eE[4];
#pragma unroll
            for (int j = 1; j < 8; ++j) af.a[j] = 0;
        }
        floatx4 a1[2] = {};
#pragma unroll
        for (int nt = 0; nt < 2; ++nt)
            a1[nt] = __builtin_amdgcn_mfma_f32_16x16x32_bf16(
                af.s, w1f[nt], a1[nt], 0, 0, 0);
        int pq = mt * 4 + q;          // pooled col
#pragma unroll
        for (int nt = 0; nt < 2; ++nt) {
            int oc = nt * 16 + r16;
            if (oc < 20) {
                floatx4 a = a1[nt];
                float v = fmaxf(fmaxf(a[0], a[1]), fmaxf(a[2], a[3])) + b1[oc];
                h1t[(c * 28 + pq) * 40 + oc] = f2bf(v);
            }
        }
    }
    __syncthreads();  // h1t complete

    // ---- conv2 via MFMA, 2 m-passes (pass A: mt w,w+4,w+8; B: w+12,w+16) --
    const u16* wtb = w2t + r16 * 32 + q * 8;
    float* hs2 = (float*)smem;  // 3600 f32 (overlays h1t rows 0..6.4)

    {   // pass A: m-tiles 0..11 (reads h1t rows 0..11)
        int abase[3];
#pragma unroll
        for (int i = 0; i < 3; ++i) {
            int m  = (w + 4 * i) * 16 + r16;
            int pq = m >> 2, sub = m & 3;
            int py = pq / 12, px2 = pq - py * 12;
            int yy = py * 2 + (sub >> 1);
            int xx = px2 * 2 + (sub & 1);
            abase[i] = (yy * 28 + xx) * 40 + q * 8;
        }
        floatx4 acc[3][4] = {};
        short8 bf[4];
#pragma unroll
        for (int nt = 0; nt < 4; ++nt)
            bf[nt] = *(const short8*)&wtb[nt * 512];
#pragma unroll 1
        for (int tap = 0; tap < 25; ++tap) {
            short8 bfn[4];
            if (tap < 24) {
#pragma unroll
                for (int nt = 0; nt < 4; ++nt)
                    bfn[nt] = *(const short8*)&wtb[(tap + 1) * 2048 + nt * 512];
            }
            int r = tap / 5, s = tap - 5 * r;
            int aoff = r * 1120 + s * 40;
#pragma unroll
            for (int i = 0; i < 3; ++i) {
                short8 af = *(const short8*)&h1t[abase[i] + aoff];
#pragma unroll
                for (int nt = 0; nt < 4; ++nt)
                    acc[i][nt] = __builtin_amdgcn_mfma_f32_16x16x32_bf16(
                        af, bf[nt], acc[i][nt], 0, 0, 0);
            }
#pragma unroll
            for (int nt = 0; nt < 4; ++nt) bf[nt] = bfn[nt];
        }
        __syncthreads();  // all pass-A h1t reads done before hs2[0,9600) writes
#pragma unroll
        for (int i = 0; i < 3; ++i) {
            int pq = (w + 4 * i) * 4 + q;   // 0..47
#pragma unroll
            for (int nt = 0; nt < 4; ++nt) {
                int oc = nt * 16 + r16;
                if (oc < 50) {
                    floatx4 a = acc[i][nt];
                    hs2[pq * 50 + oc] =
                        fmaxf(fmaxf(a[0], a[1]), fmaxf(a[2], a[3])) + b2[oc];
                }
            }
        }
    }
    {   // pass B: m-tiles 12..17 (reads h1t rows 8..15 - disjoint from hs2)
        int abase[2];
        bool vld[2];
#pragma unroll
        for (int i = 0; i < 2; ++i) {
            int mt = w + 12 + 4 * i;
            vld[i] = (mt < 18);
            int m  = (vld[i] ? mt : 12) * 16 + r16;
            int pq = m >> 2, sub = m & 3;
            int py = pq / 12, px2 = pq - py * 12;
            int yy = py * 2 + (sub >> 1);
            int xx = px2 * 2 + (sub & 1);
            abase[i] = (yy * 28 + xx) * 40 + q * 8;
        }
        floatx4 acc[2][4] = {};
        short8 bf[4];
#pragma unroll
        for (int nt = 0; nt < 4; ++nt)
            bf[nt] = *(const short8*)&wtb[nt * 512];
#pragma unroll 1
        for (int tap = 0; tap < 25; ++tap) {
            short8 bfn[4];
            if (tap < 24) {
#pragma unroll
                for (int nt = 0; nt < 4; ++nt)
                    bfn[nt] = *(const short8*)&wtb[(tap + 1) * 2048 + nt * 512];
            }
            int r = tap / 5, s = tap - 5 * r;
            int aoff = r * 1120 + s * 40;
#pragma unroll
            for (int i = 0; i < 2; ++i) {
                if (vld[i]) {
                    short8 af = *(const short8*)&h1t[abase[i] + aoff];
#pragma unroll
                    for (int nt = 0; nt < 4; ++nt)
                        acc[i][nt] = __builtin_amdgcn_mfma_f32_16x16x32_bf16(
                            af, bf[nt], acc[i][nt], 0, 0, 0);
                }
            }
#pragma unroll
            for (int nt = 0; nt < 4; ++nt) bf[nt] = bfn[nt];
        }
        // no barrier needed: writes [9600,14400) disjoint from pass-B reads
#pragma unroll
        for (int i = 0; i < 2; ++i) {
            if (vld[i]) {
                int pq = (w + 12 + 4 * i) * 4 + q;   // 48..71
#pragma unroll
                for (int nt = 0; nt < 4; ++nt) {
                    int oc = nt * 16 + r16;
                    if (oc < 50) {
                        floatx4 a = acc[i][nt];
                        hs2[pq * 50 + oc] =
                            fmaxf(fmaxf(a[0], a[1]), fmaxf(a[2], a[3])) + b2[oc];
                    }
                }
            }
        }
    }
    __syncthreads();  // hs2 complete; all h1t reads done

    // ---- zero hsbuf region [14400,39744) bytes, then pack ----
    for (int i = t; i < 6336; i += 256)
        ((u32*)smem)[3600 + i] = 0u;
    __syncthreads();

    u16* hsbuf = smem + 7200;   // [176][72] bf16, borders zero
    u32* ho = h_bf + (size_t)b * 1808;
    for (int i = t; i < 1808; i += 256) {
        if (i < 1800) {
            int k2 = 2 * i;
            u32 pk = (u32)f2bf(hs2[k2]) | ((u32)f2bf(hs2[k2 + 1]) << 16);
            ho[i] = pk;
            int pos = k2 / 50;
            int oc  = k2 - 50 * pos;      // even
            int ph  = pos / 12, pw = pos - 12 * ph;
            ((u32*)hsbuf)[((((ph + 2) * 16) + pw + 2) * 72 + oc) >> 1] = pk;
        } else ho[i] = 0u;
    }
    __syncthreads();

    // ---- pcaps via MFMA: M=72 pos (5 m-tiles), N=16 oc, K=64 ----
    int pbase[5];
#pragma unroll
    for (int mt = 0; mt < 5; ++mt) {
        int m  = mt * 16 + r16;
        int ph = m / 12, pw = m - 12 * ph;
        pbase[mt] = (ph * 16 + pw) * 72 + q * 8;
    }
    floatx4 pacc[5] = {};
    const u16* wp = w_pc + r16 * 64 + q * 8;
    const int ntap = (28 - w) >> 2;       // 7,6,6,6
#pragma unroll 1
    for (int tt = 0; tt < ntap; ++tt) {
        int tap = w + 4 * tt;
        short8 b0 = *(const short8*)&wp[tap * 1024];
        short8 b1 = *(const short8*)&wp[tap * 1024 + 32];
        int r = tap / 5, s = tap - 5 * r;
        int aoff = (r * 16 + s) * 72;
#pragma unroll
        for (int mt = 0; mt < 5; ++mt) {
            short8 a0 = *(const short8*)&hsbuf[pbase[mt] + aoff];
            short8 a1 = *(const short8*)&hsbuf[pbase[mt] + aoff + 32];
            pacc[mt] = __builtin_amdgcn_mfma_f32_16x16x32_bf16(a0, b0, pacc[mt], 0, 0, 0);
            pacc[mt] = __builtin_amdgcn_mfma_f32_16x16x32_bf16(a1, b1, pacc[mt], 0, 0, 0);
        }
    }
    __syncthreads();  // hsbuf reads done -> overlay psum

    float* psum = (float*)(smem + 7200);  // [4][80][16] f32, 20480 B
#pragma unroll
    for (int mt = 0; mt < 5; ++mt)
#pragma unroll
        for (int i = 0; i < 4; ++i) {
            int m = mt * 16 + q * 4 + i;
            psum[w * 1280 + m * 16 + r16] = pacc[mt][i];
        }
    __syncthreads();

    for (int i = t; i < 1152; i += 256) {
        float s = psum[i] + psum[1280 + i] + psum[2560 + i] + psum[3840 + i]
                + pcb[i & 15];
        psum[i] = s;
    }
    __syncthreads();

    // squash + priors -> pri[2][288] @ byte 34880
    float* pri = (float*)(smem + 17440);
    for (int r = t; r < 288; r += 256) {
        int sub = r / 72;
        int pos = r - sub * 72;
        float u0 = psum[pos * 16 + 0  + sub];
        float u1 = psum[pos * 16 + 4  + sub];
        float u2 = psum[pos * 16 + 8  + sub];
        float u3 = psum[pos * 16 + 12 + sub];
        float n2 = u0 * u0 + u1 * u1 + u2 * u2 + u3 * u3;
        float scale = (n2 / (1.0f + n2)) * rsqrtf(n2);
        u0 *= scale; u1 *= scale; u2 *= scale; u3 *= scale;
#pragma unroll
        for (int k = 0; k < 2; ++k) {
            const float4 wv = *(const float4*)&rw[(k * 288 + r) * 4];
            pri[k * 288 + r] = u0 * wv.x + u1 * wv.y + u2 * wv.z + u3 * wv.w;
        }
    }
    __syncthreads();

    // dynamic routing (3 iters): wave 0 -> k=0, wave 1 -> k=1
    if (w < 2) {
        const float* pr = &pri[w * 288];
        float p[5];
        bool  val[5];
#pragma unroll
        for (int j = 0; j < 5; ++j) {
            int r  = j * 64 + lane;
            val[j] = r < 288;
            p[j]   = val[j] ? pr[r] : 0.0f;
        }
        float tot = wave_sum(p[0] + p[1] + p[2] + p[3] + p[4]);
        float s = tot * (1.0f / 288.0f);
        float a = s * fabsf(s) / (1.0f + s * s);
#pragma unroll
        for (int it = 0; it < 2; ++it) {
            float l[5];
            float lm = -INFINITY;
#pragma unroll
            for (int j = 0; j < 5; ++j) {
                l[j] = val[j] ? p[j] * a : -INFINITY;
                lm   = fmaxf(lm, l[j]);
            }
            lm = wave_max(lm);
            float se = 0.f, sp = 0.f;
#pragma unroll
            for (int j = 0; j < 5; ++j) {
                float e = val[j] ? expf(l[j] - lm) : 0.f;
                se += e;
                sp += e * p[j];
            }
            se = wave_sum(se);
            sp = wave_sum(sp);
            float sv = sp / se;
            float v  = sv * fabsf(sv) / (1.0f + sv * sv);
            if (it == 0) a += v;
            else if (lane == 0) cbuf[b * 2 + w] = v;
        }
    }
}

// ---------- Kernel 2: fc1 32x64-tile dbuf GEMM + fused fc2 epilogue --------
// grid (64,8) = 512 blocks (2/CU). One barrier per K-iter.
__global__ __launch_bounds__(256) void k_fc1(
    const u16* __restrict__ h_bf, const u16* __restrict__ w_bf,
    const float* __restrict__ cc, const float* __restrict__ w,
    const float* __restrict__ bias, const float* __restrict__ f2w,
    float* __restrict__ out)
{
    __shared__ __align__(16) u16 As[2][32 * 40];
    __shared__ __align__(16) u16 Bs[2][64 * 40];
    const int t  = threadIdx.x;
    const int m0 = blockIdx.x * 32;
    const int n0 = blockIdx.y * 64;
    const int lane = t & 63, wv = t >> 6;
    const int r16 = lane & 15, q = lane >> 4;
    const int row = t >> 2, c8 = (t & 3) * 8;   // B loader: 64 rows x 4 grps
    const bool aload = (t < 128);               // A loader: rows 0..31
    const u16* ha = &h_bf[(size_t)(m0 + (row & 31)) * 3616 + c8];
    const u16* wa = &w_bf[(size_t)(n0 + row) * 3616 + c8];
    short8 areg = {};
    if (aload) areg = *(const short8*)ha;
    short8 breg = *(const short8*)wa;
    const int mt  = wv & 1;
    const int ntb = (wv >> 1) * 2;
    const int awr = (row & 31) * 40 + c8;
    const int bwr = row * 40 + c8;
    const int ar  = (mt * 16 + r16) * 40 + q * 8;
    const int br0 = (ntb * 16 + r16) * 40 + q * 8;
    floatx4 acc[2] = {};
#pragma unroll 1
    for (int it = 0; it < 113; ++it) {
        const int buf = it & 1;
        if (aload) *(short8*)&As[buf][awr] = areg;
        *(short8*)&Bs[buf][bwr] = breg;
        if (it < 112) {
            if (aload) areg = *(const short8*)(ha + (it + 1) * 32);
            breg = *(const short8*)(wa + (it + 1) * 32);
        }
        __syncthreads();
        short8 af = *(const short8*)&As[buf][ar];
#pragma unroll
        for (int jn = 0; jn < 2; ++jn) {
            short8 bfv = *(const short8*)&Bs[buf][br0 + jn * 640];
            acc[jn] = __builtin_amdgcn_mfma_f32_16x16x32_bf16(af, bfv, acc[jn], 0, 0, 0);
        }
    }
    // epilogue: bias + caps cols + relu, dot with fc2 rows, atomic into out
    const int mbase = m0 + mt * 16 + q * 4;
    float s0[4] = {0.f, 0.f, 0.f, 0.f};
    float s1[4] = {0.f, 0.f, 0.f, 0.f};
#pragma unroll
    for (int jn = 0; jn < 2; ++jn) {
        int n = n0 + (ntb + jn) * 16 + r16;
        if (n < 500) {
            float bn  = bias[n];
            float wc0 = w[(size_t)n * 3602 + 3600];
            float wc1 = w[(size_t)n * 3602 + 3601];
            float w20 = f2w[n];
            float w21 = f2w[502 + n];
#pragma unroll
            for (int i = 0; i < 4; ++i) {
                int m = mbase + i;
                float v = fmaxf(acc[jn][i] + bn + cc[m * 2] * wc0
                                + cc[m * 2 + 1] * wc1, 0.f);
                s0[i] += v * w20;
                s1[i] += v * w21;
            }
        }
    }
#pragma unroll
    for (int i = 0; i < 4; ++i) {
        float a0 = s0[i], a1 = s1[i];
#pragma unroll
        for (int off = 1; off <= 8; off <<= 1) {
            a0 += __shfl_xor(a0, off);
            a1 += __shfl_xor(a1, off);
        }
        if (r16 == 0) {
            int m = mbase + i;
            atomicAdd(&out[m * 2], a0);
            atomicAdd(&out[m * 2 + 1], a1);
        }
    }
}

// ---------------------------------------------------------------------------
extern "C" void kernel_launch(void* const* d_in, const int* in_sizes, int n_in,
                              void* d_out, int out_size, void* d_ws, size_t ws_size,
                              hipStream_t stream) {
    const float* x    = (const float*)d_in[0];
    const float* y    = (const float*)d_in[1];
    const float* c1w  = (const float*)d_in[2];
    const float* c1b  = (const float*)d_in[3];
    const float* c2w  = (const float*)d_in[4];
    const float* c2b  = (const float*)d_in[5];
    const float* pcw  = (const float*)d_in[6];
    const float* pcb  = (const float*)d_in[7];
    const float* rw   = (const float*)d_in[8];
    const float* f1w  = (const float*)d_in[9];
    const float* f1b  = (const float*)d_in[10];
    const float* f2w  = (const float*)d_in[11];
    const float* f2b  = (const float*)d_in[12];
    float* out = (float*)d_out;

    // workspace layout
    u32*   h_bf = (u32*)d_ws;                           // 2048*1808 u32
    u16*   w_bf = (u16*)(h_bf + (size_t)BATCH * 1808);  // 512*3616 u16
    u16*   w2t  = w_bf + (size_t)512 * 3616;            // 25*64*32 u16
    u16*   w_pc = w2t + 51200;                          // 25*16*64 u16
    u16*   w1t  = w_pc + 25600;                         // 32*32 u16
    float* cbuf = (float*)(w1t + 1024);                 // 4096 f32

    k_prep<<<548, 256, 0, stream>>>(f1w, w_bf, c2w, w2t, pcw, w_pc, c1w, w1t,
                                    y, f2w, f2b, out);
    k_convs<<<BATCH, 256, 0, stream>>>(x, w1t, c1b, w2t, c2b, w_pc, pcb, rw,
                                       h_bf, cbuf);
    dim3 g4(64, 8);
    k_fc1<<<g4, 256, 0, stream>>>((const u16*)h_bf, w_bf, cbuf, f1w, f1b,
                                  f2w, out);
}

// Round 10
// 237.195 us; speedup vs baseline: 1.1952x; 1.1952x over previous
//
#include <hip/hip_runtime.h>
#include <math.h>

// ---------------------------------------------------------------------------
// Model: conv1(5x5,20)+pool2 -> conv2(5x5,50)+pool2 -> pcaps(5x5 pad2,16)
//        -> squash -> priors -> dynamic routing(3) -> fc1(relu) -> fc2
// B=2048. conv1/conv2/pcaps/fc1 via bf16 MFMA (16x16x32).
// k_convs = round-8 structure (im2col conv1, 1-pass conv2, fused pcaps+routing).
// k_fc1: 64x64 tile, BK=64 (K padded to 3648=57*64), LDS dbuf, 1 barrier/iter,
// fused fc2 epilogue via atomics into pre-initialized out.
// h_bf POSITION-MAJOR: k' = pos*50 + oc, padded to 3648.
// ---------------------------------------------------------------------------

#define BATCH 2048
#define KP 3648          // padded K for fc1 (57 * 64)

typedef __attribute__((ext_vector_type(8))) short short8;
typedef __attribute__((ext_vector_type(4))) float floatx4;
typedef unsigned short u16;
typedef unsigned int   u32;

__device__ inline float wave_sum(float v) {
#pragma unroll
    for (int off = 32; off >= 1; off >>= 1) v += __shfl_xor(v, off);
    return v;
}
__device__ inline float wave_max(float v) {
#pragma unroll
    for (int off = 32; off >= 1; off >>= 1) v = fmaxf(v, __shfl_xor(v, off));
    return v;
}
__device__ inline u16 f2bf(float f) {  // RNE fp32->bf16 (finite)
    u32 u = __float_as_uint(f);
    u32 r = (u + 0x7FFFu + ((u >> 16) & 1u)) >> 16;
    return (u16)r;
}

// ---------- Kernel 0: weight conversions + out init ------------------------
// blk <  500 : fc1 weights row n -> w_bf[n][3648] bf16, K-permuted, via LDS
// blk == 500 : zero w_bf rows 500..511
// blk <  526 : conv2 weights -> w2t[25][64][32] bf16
// blk <  539 : pcaps weights -> w_pc[25][16][64] bf16
// blk == 539 : conv1 weights -> w1t[32][32] bf16
// blk <  548 : out[b][j] = f2b[j] + y[b,0]*f2w[j,500] + y[b,1]*f2w[j,501]
__global__ __launch_bounds__(256) void k_prep(
    const float* __restrict__ fw,  u16* __restrict__ w_bf,
    const float* __restrict__ w2,  u16* __restrict__ w2t,
    const float* __restrict__ pcw, u16* __restrict__ w_pc,
    const float* __restrict__ w1,  u16* __restrict__ w1t,
    const float* __restrict__ y,   const float* __restrict__ f2w,
    const float* __restrict__ f2b, float* __restrict__ out)
{
    __shared__ __align__(16) float srow[3600];
    const int blk = blockIdx.x, t = threadIdx.x;
    if (blk < 500) {
        const int n = blk;
        const float* src = fw + (size_t)n * 3602;
        for (int i = t; i < 1800; i += 256)
            *(float2*)&srow[2 * i] = *(const float2*)&src[2 * i];
        __syncthreads();
        u32* dst = (u32*)(w_bf + (size_t)n * KP);
        for (int i = t; i < 1824; i += 256) {
            int k2 = 2 * i;
            u32 pk = 0u;
            if (k2 < 3600) {
                int pos = k2 / 50, oc = k2 - 50 * pos;
                pk = (u32)f2bf(srow[oc * 72 + pos])
                   | ((u32)f2bf(srow[(oc + 1) * 72 + pos]) << 16);
            }
            dst[i] = pk;
        }
    } else if (blk == 500) {
        u32* z = (u32*)(w_bf + (size_t)500 * KP);
        for (int i = t; i < 21888; i += 256) z[i] = 0u;   // 12 * 1824
    } else if (blk < 526) {
        int g   = (blk - 501) * 256 + t;
        int idx = g * 8;
        int tap = idx >> 11;
        int oc  = (idx >> 5) & 63;
        int ic0 = idx & 31;
        u16 v[8];
#pragma unroll
        for (int j = 0; j < 8; ++j) {
            int ic = ic0 + j;
            float f = (ic < 20 && oc < 50) ? w2[oc * 500 + ic * 25 + tap] : 0.f;
            v[j] = f2bf(f);
        }
        *(short8*)&w2t[idx] = *(short8*)v;
    } else if (blk < 539) {
        int g = (blk - 526) * 256 + t;
        if (g >= 3200) return;
        int idx = g * 8;
        int tap = idx >> 10;
        int rem = idx & 1023;
        int oc  = rem >> 6;
        int ic0 = rem & 63;
        u16 v[8];
#pragma unroll
        for (int j = 0; j < 8; ++j) {
            int ic = ic0 + j;
            float f = (ic < 50) ? pcw[(oc * 50 + ic) * 25 + tap] : 0.f;
            v[j] = f2bf(f);
        }
        *(short8*)&w_pc[idx] = *(short8*)v;
    } else if (blk == 539) {
        if (t < 128) {
            int n  = t >> 2;
            int k0 = (t & 3) * 8;
            u16 v[8];
#pragma unroll
            for (int j = 0; j < 8; ++j) {
                int k = k0 + j;
                float f = (n < 20 && k < 25) ? w1[n * 25 + k] : 0.f;
                v[j] = f2bf(f);
            }
            *(short8*)&w1t[t * 8] = *(short8*)v;
        }
    } else {
        int b = (blk - 540) * 256 + t;   // 0..2047
        float y0 = y[b * 2], y1 = y[b * 2 + 1];
        float2 o;
        o.x = f2b[0] + y0 * f2w[500] + y1 * f2w[501];
        o.y = f2b[1] + y0 * f2w[502 + 500] + y1 * f2w[502 + 501];
        *(float2*)&out[b * 2] = o;
    }
}

// ---------- Kernel 1: conv1+conv2 (MFMA) + pcaps (MFMA) + routing ----------
// (round-8 structure; h_bf stride widened to 1824 u32)
// LDS (49408 B union):
//   conv phase : h1t[448][40] u16 | xbf[36][64] u16 | im2[112][40] u16
//   pcaps phase: hs2 f32[3600] @0 | hsbuf u16[176][72] @14400 B
//                psum f32[5120] overlays hsbuf | pri f32[576] @39744 B
__global__ __launch_bounds__(256, 3) void k_convs(
    const float* __restrict__ x, const u16* __restrict__ w1t,
    const float* __restrict__ b1, const u16* __restrict__ w2t,
    const float* __restrict__ b2, const u16* __restrict__ w_pc,
    const float* __restrict__ pcb, const float* __restrict__ rw,
    u32* __restrict__ h_bf, float* __restrict__ cbuf)
{
    __shared__ __align__(16) u16 smem[24704];
    u16* h1t = smem;            // 17920 shorts
    u16* xbf = smem + 17920;    // 2304 shorts
    u16* im2 = smem + 20224;    // 4480 shorts

    const int t = threadIdx.x;
    const int b = blockIdx.x;

    // zero the ic pad [20,32) of h1t rows; stage x as bf16
    for (int i = t; i < 2688; i += 256) {
        int pos = i / 6, c = i - 6 * pos;
        ((u32*)h1t)[pos * 20 + 10 + c] = 0u;
    }
    const float* xb = x + b * 2160;
    for (int i = t; i < 2160; i += 256) {
        int r = i / 60, c = i - 60 * r;
        xbf[r * 64 + c] = f2bf(xb[i]);
    }
    __syncthreads();

    const int lane = t & 63, w = t >> 6;
    const int r16  = lane & 15;
    const int q    = lane >> 4;

    // ---- conv1 via MFMA, 16 chunks of 2 pre-pool rows (112 positions) ----
    short8 w1f[2];
#pragma unroll
    for (int nt = 0; nt < 2; ++nt)
        w1f[nt] = *(const short8*)&w1t[(nt * 16 + r16) * 32 + q * 8];

    const int p_   = t;               // builder position (t<112)
    const int px_  = p_ >> 2;
    const int dy_  = (p_ & 3) >> 1, dx_ = p_ & 1;
    const int xc_  = 2 * px_ + dx_;
    const int j0_  = xc_ >> 1;
    const int par_ = xc_ & 1;

#pragma unroll 1
    for (int c = 0; c < 16; ++c) {
        if (t < 112) {
            u16 tap[25];
#pragma unroll
            for (int r = 0; r < 5; ++r) {
                const u32* U = (const u32*)&xbf[(2 * c + dy_ + r) * 64];
                u32 A0 = U[j0_], A1 = U[j0_ + 1], A2 = U[j0_ + 2];
                u16 e0 = par_ ? (u16)(A0 >> 16) : (u16)A0;
                u16 e1 = par_ ? (u16)A1         : (u16)(A0 >> 16);
                u16 e2 = par_ ? (u16)(A1 >> 16) : (u16)A1;
                u16 e3 = par_ ? (u16)A2         : (u16)(A1 >> 16);
                u16 e4 = par_ ? (u16)(A2 >> 16) : (u16)A2;
                tap[r * 5 + 0] = e0; tap[r * 5 + 1] = e1; tap[r * 5 + 2] = e2;
                tap[r * 5 + 3] = e3; tap[r * 5 + 4] = e4;
            }
            u32 ow[16];
#pragma unroll
            for (int j = 0; j < 12; ++j)
                ow[j] = (u32)tap[2 * j] | ((u32)tap[2 * j + 1] << 16);
            ow[12] = (u32)tap[24];
            ow[13] = 0u; ow[14] = 0u; ow[15] = 0u;
            u32* dst = (u32*)&im2[p_ * 40];
            *(uint4*)&dst[0]  = make_uint4(ow[0],  ow[1],  ow[2],  ow[3]);
            *(uint4*)&dst[4]  = make_uint4(ow[4],  ow[5],  ow[6],  ow[7]);
            *(uint4*)&dst[8]  = make_uint4(ow[8],  ow[9],  ow[10], ow[11]);
            *(uint4*)&dst[12] = make_uint4(ow[12], ow[13], ow[14], ow[15]);
        }
        __syncthreads();
#pragma unroll
        for (int mi = 0; mi < 2; ++mi) {
            int mt = w + 4 * mi;
            if (mt < 7) {
                short8 af = *(const short8*)&im2[(mt * 16 + r16) * 40 + q * 8];
                floatx4 a1[2] = {};
#pragma unroll
                for (int nt = 0; nt < 2; ++nt)
                    a1[nt] = __builtin_amdgcn_mfma_f32_16x16x32_bf16(
                        af, w1f[nt], a1[nt], 0, 0, 0);
                int pq = mt * 4 + q;
#pragma unroll
                for (int nt = 0; nt < 2; ++nt) {
                    int oc = nt * 16 + r16;
                    if (oc < 20) {
                        floatx4 a = a1[nt];
                        float v = fmaxf(fmaxf(a[0], a[1]), fmaxf(a[2], a[3]))
                                + b1[oc];
                        h1t[(c * 28 + pq) * 40 + oc] = f2bf(v);
                    }
                }
            }
        }
        __syncthreads();
    }

    // ---- conv2 via MFMA: M=288 Z-ordered pre-pool, N=64, K=32, 25 taps ----
    int abase[5];
#pragma unroll
    for (int i = 0; i < 5; ++i) {
        int mt = w + 4 * i;
        if (mt < 18) {
            int m  = mt * 16 + r16;
            int pq = m >> 2, sub = m & 3;
            int py = pq / 12, px = pq - py * 12;
            int yy = py * 2 + (sub >> 1);
            int xx = px * 2 + (sub & 1);
            abase[i] = (yy * 28 + xx) * 40 + q * 8;
        } else abase[i] = 0;
    }
    floatx4 acc2[5][4] = {};
    const u16* wtb = w2t + r16 * 32 + q * 8;

    short8 bf[4];
#pragma unroll
    for (int nt = 0; nt < 4; ++nt)
        bf[nt] = *(const short8*)&wtb[nt * 512];

#pragma unroll 1
    for (int tap = 0; tap < 25; ++tap) {
        short8 bfn[4];
        if (tap < 24) {
#pragma unroll
            for (int nt = 0; nt < 4; ++nt)
                bfn[nt] = *(const short8*)&wtb[(tap + 1) * 2048 + nt * 512];
        }
        int r = tap / 5, s = tap - 5 * r;
        int aoff = r * 1120 + s * 40;
#pragma unroll
        for (int i = 0; i < 5; ++i) {
            int mt = w + 4 * i;
            if (mt < 18) {
                short8 af = *(const short8*)&h1t[abase[i] + aoff];
#pragma unroll
                for (int nt = 0; nt < 4; ++nt)
                    acc2[i][nt] = __builtin_amdgcn_mfma_f32_16x16x32_bf16(
                        af, bf[nt], acc2[i][nt], 0, 0, 0);
            }
        }
#pragma unroll
        for (int nt = 0; nt < 4; ++nt) bf[nt] = bfn[nt];
    }
    __syncthreads();  // all A-reads of h1t done; overlay pcaps buffers

    // ---- pool -> hs2[pos*50+oc] f32 @smem[0]; zero hsbuf region ----
    float* hs2 = (float*)smem;  // 3600 f32
#pragma unroll
    for (int i = 0; i < 5; ++i) {
        int mt = w + 4 * i;
        if (mt < 18) {
            int pq = mt * 4 + q;
#pragma unroll
            for (int nt = 0; nt < 4; ++nt) {
                int oc = nt * 16 + r16;
                if (oc < 50) {
                    floatx4 a = acc2[i][nt];
                    hs2[pq * 50 + oc] =
                        fmaxf(fmaxf(a[0], a[1]), fmaxf(a[2], a[3])) + b2[oc];
                }
            }
        }
    }
    for (int i = t; i < 6336; i += 256)   // zero hsbuf [14400,39744) bytes
        ((u32*)smem)[3600 + i] = 0u;
    __syncthreads();

    // ---- pack h_bf (global, stride 1824 u32) + fill hsbuf interior ----
    u16* hsbuf = smem + 7200;             // [176][72] bf16, borders zero
    u32* ho = h_bf + (size_t)b * 1824;
    for (int i = t; i < 1824; i += 256) {
        if (i < 1800) {
            int k2 = 2 * i;
            u32 pk = (u32)f2bf(hs2[k2]) | ((u32)f2bf(hs2[k2 + 1]) << 16);
            ho[i] = pk;
            int pos = k2 / 50;
            int oc  = k2 - 50 * pos;      // even
            int ph  = pos / 12, pw = pos - 12 * ph;
            ((u32*)hsbuf)[((((ph + 2) * 16) + pw + 2) * 72 + oc) >> 1] = pk;
        } else ho[i] = 0u;
    }
    __syncthreads();

    // ---- pcaps via MFMA: M=72 pos (5 m-tiles), N=16 oc, K=64 ----
    int pbase[5];
#pragma unroll
    for (int mt = 0; mt < 5; ++mt) {
        int m  = mt * 16 + r16;
        int ph = m / 12, pw = m - 12 * ph;
        pbase[mt] = (ph * 16 + pw) * 72 + q * 8;
    }
    floatx4 pacc[5] = {};
    const u16* wp = w_pc + r16 * 64 + q * 8;
    const int ntap = (28 - w) >> 2;       // 7,6,6,6
#pragma unroll 1
    for (int tt = 0; tt < ntap; ++tt) {
        int tap = w + 4 * tt;
        short8 b0 = *(const short8*)&wp[tap * 1024];
        short8 b1 = *(const short8*)&wp[tap * 1024 + 32];
        int r = tap / 5, s = tap - 5 * r;
        int aoff = (r * 16 + s) * 72;
#pragma unroll
        for (int mt = 0; mt < 5; ++mt) {
            short8 a0 = *(const short8*)&hsbuf[pbase[mt] + aoff];
            short8 a1 = *(const short8*)&hsbuf[pbase[mt] + aoff + 32];
            pacc[mt] = __builtin_amdgcn_mfma_f32_16x16x32_bf16(a0, b0, pacc[mt], 0, 0, 0);
            pacc[mt] = __builtin_amdgcn_mfma_f32_16x16x32_bf16(a1, b1, pacc[mt], 0, 0, 0);
        }
    }
    __syncthreads();  // hsbuf reads done -> overlay psum

    float* psum = (float*)(smem + 7200);  // [4][80][16] f32
#pragma unroll
    for (int mt = 0; mt < 5; ++mt)
#pragma unroll
        for (int i = 0; i < 4; ++i) {
            int m = mt * 16 + q * 4 + i;
            psum[w * 1280 + m * 16 + r16] = pacc[mt][i];
        }
    __syncthreads();

    for (int i = t; i < 1152; i += 256) {
        float s = psum[i] + psum[1280 + i] + psum[2560 + i] + psum[3840 + i]
                + pcb[i & 15];
        psum[i] = s;
    }
    __syncthreads();

    // squash + priors -> pri[2][288]
    float* pri = (float*)(smem + 19872);
    for (int r = t; r < 288; r += 256) {
        int sub = r / 72;
        int pos = r - sub * 72;
        float u0 = psum[pos * 16 + 0  + sub];
        float u1 = psum[pos * 16 + 4  + sub];
        float u2 = psum[pos * 16 + 8  + sub];
        float u3 = psum[pos * 16 + 12 + sub];
        float n2 = u0 * u0 + u1 * u1 + u2 * u2 + u3 * u3;
        float scale = (n2 / (1.0f + n2)) * rsqrtf(n2);
        u0 *= scale; u1 *= scale; u2 *= scale; u3 *= scale;
#pragma unroll
        for (int k = 0; k < 2; ++k) {
            const float4 wv = *(const float4*)&rw[(k * 288 + r) * 4];
            pri[k * 288 + r] = u0 * wv.x + u1 * wv.y + u2 * wv.z + u3 * wv.w;
        }
    }
    __syncthreads();

    // dynamic routing (3 iters): wave 0 -> k=0, wave 1 -> k=1
    if (w < 2) {
        const float* pr = &pri[w * 288];
        float p[5];
        bool  val[5];
#pragma unroll
        for (int j = 0; j < 5; ++j) {
            int r  = j * 64 + lane;
            val[j] = r < 288;
            p[j]   = val[j] ? pr[r] : 0.0f;
        }
        float tot = wave_sum(p[0] + p[1] + p[2] + p[3] + p[4]);
        float s = tot * (1.0f / 288.0f);
        float a = s * fabsf(s) / (1.0f + s * s);
#pragma unroll
        for (int it = 0; it < 2; ++it) {
            float l[5];
            float lm = -INFINITY;
#pragma unroll
            for (int j = 0; j < 5; ++j) {
                l[j] = val[j] ? p[j] * a : -INFINITY;
                lm   = fmaxf(lm, l[j]);
            }
            lm = wave_max(lm);
            float se = 0.f, sp = 0.f;
#pragma unroll
            for (int j = 0; j < 5; ++j) {
                float e = val[j] ? expf(l[j] - lm) : 0.f;
                se += e;
                sp += e * p[j];
            }
            se = wave_sum(se);
            sp = wave_sum(sp);
            float sv = sp / se;
            float v  = sv * fabsf(sv) / (1.0f + sv * sv);
            if (it == 0) a += v;
            else if (lane == 0) cbuf[b * 2 + w] = v;
        }
    }
}

// ---------- Kernel 2: fc1 64x64-tile BK=64 dbuf GEMM + fused fc2 -----------
// grid (32,8) = 256 blocks. 57 K-iters, one barrier each.
// wave wv: m-tile wv (16 rows) x all 4 n-tiles; 8 MFMAs per iter.
__global__ __launch_bounds__(256) void k_fc1(
    const u16* __restrict__ h_bf, const u16* __restrict__ w_bf,
    const float* __restrict__ cc, const float* __restrict__ w,
    const float* __restrict__ bias, const float* __restrict__ f2w,
    float* __restrict__ out)
{
    __shared__ __align__(16) u16 As[2][64 * 72];  // pitch 72 shorts (144 B)
    __shared__ __align__(16) u16 Bs[2][64 * 72];
    const int t  = threadIdx.x;
    const int m0 = blockIdx.x * 64;
    const int n0 = blockIdx.y * 64;
    const int row = t >> 2, seg = t & 3;          // 64 rows x 4 segs of 16
    const u16* ha = &h_bf[(size_t)(m0 + row) * KP + seg * 16];
    const u16* wa = &w_bf[(size_t)(n0 + row) * KP + seg * 16];
    short8 a0 = *(const short8*)ha;
    short8 a1 = *(const short8*)(ha + 8);
    short8 b0 = *(const short8*)wa;
    short8 b1 = *(const short8*)(wa + 8);
    const int lane = t & 63, wv = t >> 6;
    const int r16 = lane & 15, q = lane >> 4;
    const int wr = row * 72 + seg * 16;
    const int ar = (wv * 16 + r16) * 72 + q * 8;
    const int br = r16 * 72 + q * 8;
    floatx4 acc[4] = {};
#pragma unroll 1
    for (int it = 0; it < 57; ++it) {
        const int buf = it & 1;
        *(short8*)&As[buf][wr]     = a0;
        *(short8*)&As[buf][wr + 8] = a1;
        *(short8*)&Bs[buf][wr]     = b0;
        *(short8*)&Bs[buf][wr + 8] = b1;
        if (it < 56) {
            const u16* han = ha + (it + 1) * 64;
            const u16* wan = wa + (it + 1) * 64;
            a0 = *(const short8*)han;
            a1 = *(const short8*)(han + 8);
            b0 = *(const short8*)wan;
            b1 = *(const short8*)(wan + 8);
        }
        __syncthreads();
#pragma unroll
        for (int s = 0; s < 2; ++s) {
            short8 af = *(const short8*)&As[buf][ar + s * 32];
#pragma unroll
            for (int nt = 0; nt < 4; ++nt) {
                short8 bfv = *(const short8*)&Bs[buf][br + nt * 1152 + s * 32];
                acc[nt] = __builtin_amdgcn_mfma_f32_16x16x32_bf16(
                    af, bfv, acc[nt], 0, 0, 0);
            }
        }
    }
    // epilogue: bias + caps cols + relu, dot with fc2 rows, atomic into out
    const int mbase = m0 + wv * 16 + q * 4;
    float s0[4] = {0.f, 0.f, 0.f, 0.f};
    float s1[4] = {0.f, 0.f, 0.f, 0.f};
#pragma unroll
    for (int nt = 0; nt < 4; ++nt) {
        int n = n0 + nt * 16 + r16;
        if (n < 500) {
            float bn  = bias[n];
            float wc0 = w[(size_t)n * 3602 + 3600];
            float wc1 = w[(size_t)n * 3602 + 3601];
            float w20 = f2w[n];
            float w21 = f2w[502 + n];
#pragma unroll
            for (int i = 0; i < 4; ++i) {
                int m = mbase + i;
                float v = fmaxf(acc[nt][i] + bn + cc[m * 2] * wc0
                                + cc[m * 2 + 1] * wc1, 0.f);
                s0[i] += v * w20;
                s1[i] += v * w21;
            }
        }
    }
#pragma unroll
    for (int i = 0; i < 4; ++i) {
        float a0r = s0[i], a1r = s1[i];
#pragma unroll
        for (int off = 1; off <= 8; off <<= 1) {
            a0r += __shfl_xor(a0r, off);
            a1r += __shfl_xor(a1r, off);
        }
        if (r16 == 0) {
            int m = mbase + i;
            atomicAdd(&out[m * 2], a0r);
            atomicAdd(&out[m * 2 + 1], a1r);
        }
    }
}

// ---------------------------------------------------------------------------
extern "C" void kernel_launch(void* const* d_in, const int* in_sizes, int n_in,
                              void* d_out, int out_size, void* d_ws, size_t ws_size,
                              hipStream_t stream) {
    const float* x    = (const float*)d_in[0];
    const float* y    = (const float*)d_in[1];
    const float* c1w  = (const float*)d_in[2];
    const float* c1b  = (const float*)d_in[3];
    const float* c2w  = (const float*)d_in[4];
    const float* c2b  = (const float*)d_in[5];
    const float* pcw  = (const float*)d_in[6];
    const float* pcb  = (const float*)d_in[7];
    const float* rw   = (const float*)d_in[8];
    const float* f1w  = (const float*)d_in[9];
    const float* f1b  = (const float*)d_in[10];
    const float* f2w  = (const float*)d_in[11];
    const float* f2b  = (const float*)d_in[12];
    float* out = (float*)d_out;

    // workspace layout
    u32*   h_bf = (u32*)d_ws;                           // 2048*1824 u32
    u16*   w_bf = (u16*)(h_bf + (size_t)BATCH * 1824);  // 512*3648 u16
    u16*   w2t  = w_bf + (size_t)512 * KP;              // 25*64*32 u16
    u16*   w_pc = w2t + 51200;                          // 25*16*64 u16
    u16*   w1t  = w_pc + 25600;                         // 32*32 u16
    float* cbuf = (float*)(w1t + 1024);                 // 4096 f32

    k_prep<<<548, 256, 0, stream>>>(f1w, w_bf, c2w, w2t, pcw, w_pc, c1w, w1t,
                                    y, f2w, f2b, out);
    k_convs<<<BATCH, 256, 0, stream>>>(x, w1t, c1b, w2t, c2b, w_pc, pcb, rw,
                                       h_bf, cbuf);
    dim3 g4(32, 8);
    k_fc1<<<g4, 256, 0, stream>>>((const u16*)h_bf, w_bf, cbuf, f1w, f1b,
                                  f2w, out);
}